// Round 15
// baseline (619.758 us; speedup 1.0000x reference)
//
#include <hip/hip_runtime.h>
#include <hip/hip_fp16.h>
#include <cstdint>
#include <cstddef>

#define NN 100000      // nodes
#define NE 1600000     // edges
#define HID 100
#define INF 16

typedef _Float16 f16x8 __attribute__((ext_vector_type(8)));
typedef float f32x4 __attribute__((ext_vector_type(4)));

// ---- fp16 helpers (h stored fp16; all accumulation fp32) ----
__device__ __forceinline__ float2 up_f16(unsigned int u) {
  __half2 h = *reinterpret_cast<const __half2*>(&u);
  return __half22float2(h);
}
__device__ __forceinline__ unsigned int pk_f16(float lo, float hi) {
  __half2 h = __floats2half2_rn(lo, hi);
  return *reinterpret_cast<const unsigned int*>(&h);
}
__device__ __forceinline__ f16x8 as_f16x8(uint4 v) {
  union { uint4 u; f16x8 f; } c; c.u = v; return c.f;
}

// ---------------- CSR build (R9 scheme; R13: privatization = null result,
// ~70us is the 1.6M-random-atomic floor) ----------------
__global__ void k_hist(const int* __restrict__ dst, int* __restrict__ deg,
                       int* __restrict__ rank) {
  int e = blockIdx.x * 256 + threadIdx.x;
  if (e < NE) rank[e] = atomicAdd(&deg[dst[e]], 1);
}

__global__ void k_scan1(const int* __restrict__ deg, int* __restrict__ offs,
                        int* __restrict__ bsum) {
  __shared__ int s[256];
  int t = threadIdx.x;
  int i = blockIdx.x * 256 + t;
  int v = (i < NN) ? deg[i] : 0;
  s[t] = v; __syncthreads();
  for (int off = 1; off < 256; off <<= 1) {
    int x = (t >= off) ? s[t - off] : 0;
    __syncthreads();
    s[t] += x;
    __syncthreads();
  }
  if (i < NN) offs[i] = s[t] - v;
  if (t == 255) bsum[blockIdx.x] = s[255];
}

__global__ void k_scan2(int* __restrict__ bsum, int nb) {
  __shared__ int s[512];
  int t = threadIdx.x;
  int v = (t < nb) ? bsum[t] : 0;
  s[t] = v; __syncthreads();
  for (int off = 1; off < 512; off <<= 1) {
    int x = (t >= off) ? s[t - off] : 0;
    __syncthreads();
    s[t] += x;
    __syncthreads();
  }
  if (t < nb) bsum[t] = s[t] - v;
}

__global__ void k_scan3(int* __restrict__ offs, const int* __restrict__ bsum) {
  int i = blockIdx.x * 256 + threadIdx.x;
  if (i < NN) offs[i] += bsum[i >> 8];
  else if (i == NN) offs[NN] = NE;
}

__global__ void k_fill(const int* __restrict__ src, const int* __restrict__ dst,
                       const float* __restrict__ ef, const int* __restrict__ offs,
                       const int* __restrict__ rank,
                       unsigned long long* __restrict__ epack) {
  int e = blockIdx.x * 256 + threadIdx.x;
  if (e >= NE) return;
  int p = offs[dst[e]] + rank[e];
  unsigned long long v = (unsigned int)src[e] |
                         ((unsigned long long)(unsigned int)__float_as_int(ef[e]) << 32);
  epack[p] = v;
}

// ---- W pre-pack into per-lane MFMA B-fragments (fp16), all 3 layers ----
__device__ __forceinline__ float wval(const float* W, int kp, int col) {
  if (col >= HID) return 0.f;
  if (kp < 128) return (kp < 100) ? W[kp * HID + col] : 0.f;
  int k2 = kp - 128;
  return (k2 < 100) ? W[(100 + k2) * HID + col] : 0.f;
}
__global__ void k_wpack3(const float* __restrict__ W1, const float* __restrict__ W2,
                         const float* __restrict__ W3, uint4* __restrict__ Bp) {
  int tid = blockIdx.x * 256 + threadIdx.x;
  if (tid >= 3 * 3584) return;
  int l = tid / 3584, r = tid % 3584;
  const float* W = (l == 0) ? W1 : (l == 1) ? W2 : W3;
  int lane = r & 63, f = r >> 6;
  int s = f / 7, n = f % 7;
  int col = n * 16 + (lane & 15);
  int kb = s * 32 + (lane >> 4) * 8;
  unsigned int u0 = pk_f16(wval(W, kb + 0, col), wval(W, kb + 1, col));
  unsigned int u1 = pk_f16(wval(W, kb + 2, col), wval(W, kb + 3, col));
  unsigned int u2 = pk_f16(wval(W, kb + 4, col), wval(W, kb + 5, col));
  unsigned int u3 = pk_f16(wval(W, kb + 6, col), wval(W, kb + 7, col));
  Bp[tid] = make_uint4(u0, u1, u2, u3);
}

// ---------------- lift: h16 = fp16(tanh(x @ Wl + bl)), LDS-coalesced store ----------------
__global__ __launch_bounds__(256) void k_lift(const float* __restrict__ x,
                                              const float* __restrict__ Wl,
                                              const float* __restrict__ bl,
                                              unsigned short* __restrict__ h16) {
  __shared__ uint2 sh[256][25];     // 51,200 B
  int t = threadIdx.x;
  int n = blockIdx.x * 256 + t;
  int nc = n < NN ? n : NN - 1;
  const float4* W4 = (const float4*)Wl;
  const float4* b4 = (const float4*)bl;
  float4 acc[25];
  #pragma unroll
  for (int j = 0; j < 25; ++j) acc[j] = b4[j];
  const float4* xr = (const float4*)(x + (size_t)nc * INF);
  for (int k4 = 0; k4 < 4; ++k4) {
    float4 xv = xr[k4];
    #pragma unroll
    for (int c = 0; c < 4; ++c) {
      float xs = (&xv.x)[c];
      int k = k4 * 4 + c;
      #pragma unroll
      for (int j = 0; j < 25; ++j) {
        acc[j].x = fmaf(xs, W4[k * 25 + j].x, acc[j].x);
        acc[j].y = fmaf(xs, W4[k * 25 + j].y, acc[j].y);
        acc[j].z = fmaf(xs, W4[k * 25 + j].z, acc[j].z);
        acc[j].w = fmaf(xs, W4[k * 25 + j].w, acc[j].w);
      }
    }
  }
  #pragma unroll
  for (int j = 0; j < 25; ++j) {
    float4 v = acc[j];
    sh[t][j] = make_uint2(pk_f16(tanhf(v.x), tanhf(v.y)),
                          pk_f16(tanhf(v.z), tanhf(v.w)));
  }
  __syncthreads();
  const uint4* shv = (const uint4*)sh;
  uint4* ov = (uint4*)h16;
  size_t gbase = (size_t)blockIdx.x * 3200;
  #pragma unroll
  for (int i = 0; i < 13; ++i) {
    int idx = i * 256 + t;
    if (idx < 3200 && gbase + idx < 1250000) ov[gbase + idx] = shv[idx];
  }
}

// ---- shared device body: stage h + gather-reduce into LDS + MFMA ----
// Block = 64 nodes, 4 waves. Phase A: stage h rows (dword cols 0..49) + zero
// K-pads. Phase B: wave w gather-reduces its 16 nodes (unroll x8, R14
// structure) writing fp16 accs directly into xs cols 64..113 -> the red16
// global round-trip is eliminated. Phase C: MFMA as before.
// C/D mapping (m89-verified): col = lane&15, row = (lane>>4)*4 + reg.
__device__ __forceinline__ void layer_core(const unsigned short* __restrict__ h16,
                                           const int* __restrict__ offs,
                                           const int2* __restrict__ ep,
                                           const uint4* __restrict__ Bpk,
                                           const float* __restrict__ bias,
                                           unsigned int* xs, f32x4 (&acc)[7],
                                           int t, int w, int lane, int blk) {
  const size_t base2 = (size_t)blk * 3200;
  const size_t limit2 = (size_t)NN * 50;
  const unsigned int* hp = (const unsigned int*)h16;

  for (int i = t; i < 64 * 28; i += 256) {
    int row = i / 28, c = i % 28;
    int col = (c < 14) ? (50 + c) : (100 + c);
    xs[row * 132 + col] = 0;
  }
  for (int i = t; i < 3200; i += 256) {
    int row = i / 50, c = i % 50;
    size_t g = base2 + i; if (g >= limit2) g = limit2 - 1;
    xs[row * 132 + c] = hp[g];
  }

  // ---- gather-reduce: wave w handles rows w*16 .. w*16+15 ----
  const uint2* __restrict__ h2 = (const uint2*)h16;
  int lc = lane < 25 ? lane : 24;
  for (int j = 0; j < 16; ++j) {
    int gn = blk * 64 + (w << 4) + j;
    int node = __builtin_amdgcn_readfirstlane(gn < NN ? gn : NN - 1);
    int beg = offs[node], end = offs[node + 1];
    float4 a = make_float4(0.f, 0.f, 0.f, 0.f);
    int i = beg;
    for (; i + 8 <= end; i += 8) {
      int2 e0 = ep[i + 0], e1 = ep[i + 1], e2 = ep[i + 2], e3 = ep[i + 3];
      int2 e4 = ep[i + 4], e5 = ep[i + 5], e6 = ep[i + 6], e7 = ep[i + 7];
      uint2 v0 = h2[(size_t)e0.x * 25 + lc];
      uint2 v1 = h2[(size_t)e1.x * 25 + lc];
      uint2 v2 = h2[(size_t)e2.x * 25 + lc];
      uint2 v3 = h2[(size_t)e3.x * 25 + lc];
      uint2 v4 = h2[(size_t)e4.x * 25 + lc];
      uint2 v5 = h2[(size_t)e5.x * 25 + lc];
      uint2 v6 = h2[(size_t)e6.x * 25 + lc];
      uint2 v7 = h2[(size_t)e7.x * 25 + lc];
      float w0 = __int_as_float(e0.y), w1 = __int_as_float(e1.y);
      float w2 = __int_as_float(e2.y), w3 = __int_as_float(e3.y);
      float w4 = __int_as_float(e4.y), w5 = __int_as_float(e5.y);
      float w6 = __int_as_float(e6.y), w7 = __int_as_float(e7.y);
      float2 a0 = up_f16(v0.x), b0 = up_f16(v0.y);
      float2 a1 = up_f16(v1.x), b1 = up_f16(v1.y);
      float2 a2 = up_f16(v2.x), b2 = up_f16(v2.y);
      float2 a3 = up_f16(v3.x), b3 = up_f16(v3.y);
      float2 a4 = up_f16(v4.x), b4 = up_f16(v4.y);
      float2 a5 = up_f16(v5.x), b5 = up_f16(v5.y);
      float2 a6 = up_f16(v6.x), b6 = up_f16(v6.y);
      float2 a7 = up_f16(v7.x), b7 = up_f16(v7.y);
      a.x = fmaf(w0, a0.x, a.x); a.y = fmaf(w0, a0.y, a.y);
      a.z = fmaf(w0, b0.x, a.z); a.w = fmaf(w0, b0.y, a.w);
      a.x = fmaf(w1, a1.x, a.x); a.y = fmaf(w1, a1.y, a.y);
      a.z = fmaf(w1, b1.x, a.z); a.w = fmaf(w1, b1.y, a.w);
      a.x = fmaf(w2, a2.x, a.x); a.y = fmaf(w2, a2.y, a.y);
      a.z = fmaf(w2, b2.x, a.z); a.w = fmaf(w2, b2.y, a.w);
      a.x = fmaf(w3, a3.x, a.x); a.y = fmaf(w3, a3.y, a.y);
      a.z = fmaf(w3, b3.x, a.z); a.w = fmaf(w3, b3.y, a.w);
      a.x = fmaf(w4, a4.x, a.x); a.y = fmaf(w4, a4.y, a.y);
      a.z = fmaf(w4, b4.x, a.z); a.w = fmaf(w4, b4.y, a.w);
      a.x = fmaf(w5, a5.x, a.x); a.y = fmaf(w5, a5.y, a.y);
      a.z = fmaf(w5, b5.x, a.z); a.w = fmaf(w5, b5.y, a.w);
      a.x = fmaf(w6, a6.x, a.x); a.y = fmaf(w6, a6.y, a.y);
      a.z = fmaf(w6, b6.x, a.z); a.w = fmaf(w6, b6.y, a.w);
      a.x = fmaf(w7, a7.x, a.x); a.y = fmaf(w7, a7.y, a.y);
      a.z = fmaf(w7, b7.x, a.z); a.w = fmaf(w7, b7.y, a.w);
    }
    for (; i < end; ++i) {
      int2 e0 = ep[i];
      uint2 v0 = h2[(size_t)e0.x * 25 + lc];
      float w0 = __int_as_float(e0.y);
      float2 a0 = up_f16(v0.x), b0 = up_f16(v0.y);
      a.x = fmaf(w0, a0.x, a.x); a.y = fmaf(w0, a0.y, a.y);
      a.z = fmaf(w0, b0.x, a.z); a.w = fmaf(w0, b0.y, a.w);
    }
    if (lane < 25) {
      int row = (w << 4) + j;
      xs[row * 132 + 64 + 2 * lc] = pk_f16(a.x, a.y);
      xs[row * 132 + 64 + 2 * lc + 1] = pk_f16(a.z, a.w);
    }
  }
  __syncthreads();

  // ---- MFMA phase ----
  const int rowA = (w << 4) + (lane & 15);
  const int kg = lane >> 4;
  #pragma unroll
  for (int n = 0; n < 7; ++n) {
    int c = n * 16 + (lane & 15);
    float bv = (c < HID) ? bias[c] : 0.f;
    acc[n] = (f32x4){bv, bv, bv, bv};
  }
  const uint4* bp = Bpk + lane;
  #pragma unroll
  for (int s = 0; s < 8; ++s) {
    uint4 av = *reinterpret_cast<const uint4*>(&xs[rowA * 132 + s * 16 + kg * 4]);
    f16x8 af = as_f16x8(av);
    #pragma unroll
    for (int n = 0; n < 7; ++n) {
      f16x8 bf = as_f16x8(bp[(s * 7 + n) * 64]);
      acc[n] = __builtin_amdgcn_mfma_f32_16x16x32_f16(af, bf, acc[n], 0, 0, 0);
    }
  }
}

// -------- fused layer (1,2): out16 = fp16(relu([h | reduce(h)] @ W + b)) --------
__global__ __launch_bounds__(256) void k_layer(const unsigned short* __restrict__ h16,
                                               const int* __restrict__ offs,
                                               const int2* __restrict__ ep,
                                               const uint4* __restrict__ Bpk,
                                               const float* __restrict__ bias,
                                               unsigned short* __restrict__ out16) {
  __shared__ unsigned int xs[64 * 132];
  const int t = threadIdx.x;
  const int w = t >> 6, lane = t & 63;
  const int blk = blockIdx.x;
  f32x4 acc[7];
  layer_core(h16, offs, ep, Bpk, bias, xs, acc, t, w, lane, blk);

  const int kg = lane >> 4;
  const int orow0 = blk * 64 + (w << 4) + (kg << 2);
  const int ocol = lane & 15;
  #pragma unroll
  for (int n = 0; n < 7; ++n) {
    int c = n * 16 + ocol;
    if (c < HID) {
      #pragma unroll
      for (int q = 0; q < 4; ++q) {
        int rr = orow0 + q;
        if (rr < NN) {
          float v = fmaxf(acc[n][q], 0.f);
          out16[(size_t)rr * HID + c] = __half_as_ushort(__float2half(v));
        }
      }
    }
  }
}

// -------- fused layer 3 + output head: out = sigmoid(relu(...) @ Wo + bo) --------
// relu'd C-fragments -> LDS fp32 [64][104] -> 4 threads/row dot Wo ->
// shfl_xor reduce -> sigmoid store. hB16 never materialized.
__global__ __launch_bounds__(256) void k_layer_out(const unsigned short* __restrict__ h16,
                                                   const int* __restrict__ offs,
                                                   const int2* __restrict__ ep,
                                                   const uint4* __restrict__ Bpk,
                                                   const float* __restrict__ bias,
                                                   const float* __restrict__ Wo,
                                                   const float* __restrict__ bo,
                                                   float* __restrict__ out) {
  __shared__ unsigned int xs[64 * 132];
  const int t = threadIdx.x;
  const int w = t >> 6, lane = t & 63;
  const int blk = blockIdx.x;
  f32x4 acc[7];
  layer_core(h16, offs, ep, Bpk, bias, xs, acc, t, w, lane, blk);
  __syncthreads();   // all waves done reading xs before reuse as fp32

  float* xf = (float*)xs;            // [64][104] = 26,624 B <= 33,792 B
  const int kg = lane >> 4;
  const int orl = (w << 4) + (kg << 2);  // local row base
  const int ocol = lane & 15;
  #pragma unroll
  for (int n = 0; n < 7; ++n) {
    int c = n * 16 + ocol;
    if (c < HID) {
      #pragma unroll
      for (int q = 0; q < 4; ++q) xf[(orl + q) * 104 + c] = fmaxf(acc[n][q], 0.f);
    }
  }
  __syncthreads();

  int row = t >> 2, seg = t & 3;     // 4 threads per row, 25 cols each
  int gn = blk * 64 + row;
  float s0 = 0.f, s1 = 0.f, s2 = 0.f;
  int cbase = seg * 25;
  #pragma unroll
  for (int k = 0; k < 25; ++k) {
    float v = xf[row * 104 + cbase + k];
    s0 = fmaf(v, Wo[(cbase + k) * 3 + 0], s0);
    s1 = fmaf(v, Wo[(cbase + k) * 3 + 1], s1);
    s2 = fmaf(v, Wo[(cbase + k) * 3 + 2], s2);
  }
  s0 += __shfl_xor(s0, 1); s0 += __shfl_xor(s0, 2);
  s1 += __shfl_xor(s1, 1); s1 += __shfl_xor(s1, 2);
  s2 += __shfl_xor(s2, 1); s2 += __shfl_xor(s2, 2);
  if (seg == 0 && gn < NN) {
    out[(size_t)gn * 3 + 0] = 1.f / (1.f + expf(-(s0 + bo[0])));
    out[(size_t)gn * 3 + 1] = 1.f / (1.f + expf(-(s1 + bo[1])));
    out[(size_t)gn * 3 + 2] = 1.f / (1.f + expf(-(s2 + bo[2])));
  }
}

extern "C" void kernel_launch(void* const* d_in, const int* in_sizes, int n_in,
                              void* d_out, int out_size, void* d_ws, size_t ws_size,
                              hipStream_t stream) {
  const float* x  = (const float*)d_in[0];
  const float* ef = (const float*)d_in[1];
  const int*   src = (const int*)d_in[2];
  const int*   dst = (const int*)d_in[3];
  const float* Wl = (const float*)d_in[4];
  const float* bl = (const float*)d_in[5];
  const float* W1 = (const float*)d_in[6];
  const float* b1 = (const float*)d_in[7];
  const float* W2 = (const float*)d_in[8];
  const float* b2 = (const float*)d_in[9];
  const float* W3 = (const float*)d_in[10];
  const float* b3 = (const float*)d_in[11];
  const float* Wo = (const float*)d_in[12];
  const float* bo = (const float*)d_in[13];
  float* out = (float*)d_out;

  // workspace layout (~93.6 MB)
  char* ws = (char*)d_ws;
  int*            rank   = (int*)ws;                            // 6,400,000 B
  uint4*          Wpk    = (uint4*)(ws + 20000000);             // 3 x 57,344 B contiguous
  unsigned short* hA16   = (unsigned short*)(ws + 40000000);    // 20,000,000 B
  unsigned short* hB16   = (unsigned short*)(ws + 60000000);    // 20,000,000 B
  int*            offs   = (int*)(ws + 80000000);               // (NN+1)*4
  int*            deg    = (int*)(ws + 80400128);               // NN*4
  unsigned long long* epack = (unsigned long long*)(ws + 80800256); // NE*8
  int*            bsum   = (int*)(ws + 93600256);               // 391*4

  const int scanBlocks  = (NN + 255) / 256;         // 391
  const int layerBlocks = (NN + 63) / 64;           // 1563

  // ---- CSR build (simple hist + rank trick, atomic-free fill) ----
  hipMemsetAsync(deg, 0, NN * sizeof(int), stream);
  k_hist <<<(NE + 255) / 256, 256, 0, stream>>>(dst, deg, rank);
  k_scan1<<<scanBlocks, 256, 0, stream>>>(deg, offs, bsum);
  k_scan2<<<1, 512, 0, stream>>>(bsum, scanBlocks);
  k_scan3<<<scanBlocks, 256, 0, stream>>>(offs, bsum);
  k_fill <<<(NE + 255) / 256, 256, 0, stream>>>(src, dst, ef, offs, rank, epack);

  // ---- W fragment pre-pack (all 3 layers, one launch) ----
  k_wpack3<<<42, 256, 0, stream>>>(W1, W2, W3, Wpk);

  // ---- network (fused reduce+mlp per layer; layer 3 fused with out head) ----
  k_lift<<<scanBlocks, 256, 0, stream>>>(x, Wl, bl, hA16);

  k_layer    <<<layerBlocks, 256, 0, stream>>>(hA16, offs, (const int2*)epack,
                                               Wpk, b1, hB16);
  k_layer    <<<layerBlocks, 256, 0, stream>>>(hB16, offs, (const int2*)epack,
                                               Wpk + 3584, b2, hA16);
  k_layer_out<<<layerBlocks, 256, 0, stream>>>(hA16, offs, (const int2*)epack,
                                               Wpk + 7168, b3, Wo, bo, out);
}